// Round 4
// baseline (497.487 us; speedup 1.0000x reference)
//
#include <hip/hip_runtime.h>
#include <hip/hip_bf16.h>

#define B_N   16384
#define D_N   17
#define H_N   256
#define E_N   64

typedef __attribute__((ext_vector_type(8))) short bf16x8;
typedef __attribute__((ext_vector_type(4))) float f32x4;

static __device__ __forceinline__ short f2bf(float f){
  unsigned u = __builtin_bit_cast(unsigned, f);
  unsigned r = (u + 0x7fffu + ((u >> 16) & 1u)) >> 16;   // RNE
  return (short)(unsigned short)r;
}
static __device__ __forceinline__ float bf2f(short s){
  unsigned u = ((unsigned)(unsigned short)s) << 16;
  return __builtin_bit_cast(float, u);
}
static __device__ __forceinline__ float lrelu(float v){ return v >= 0.f ? v : 0.01f * v; }

// ---------- prep: fp32 (G,R,C) -> bf16 (G,C,R) ----------
__global__ void transpose_convert(const float* __restrict__ in, short* __restrict__ outp,
                                  int R, int C){
  __shared__ float tile[32][33];
  int g = blockIdx.z;
  const float* inp = in + (size_t)g * R * C;
  short* op = outp + (size_t)g * R * C;
  int c0 = blockIdx.x * 32, r0 = blockIdx.y * 32;
  for (int i = threadIdx.y; i < 32; i += 8)
    tile[i][threadIdx.x] = inp[(size_t)(r0 + i) * C + c0 + threadIdx.x];
  __syncthreads();
  for (int i = threadIdx.y; i < 32; i += 8)
    op[(size_t)(c0 + i) * R + r0 + threadIdx.x] = f2bf(tile[threadIdx.x][i]);
}

// ---------- prep: stack+convert Wq|Wk|Wv -> bf16 [192][64] ----------
__global__ void convert_wqkv(const float* __restrict__ Wq, const float* __restrict__ Wk,
                             const float* __restrict__ Wv, short* __restrict__ outw){
  int i = blockIdx.x * 256 + threadIdx.x;        // 0..12287
  int g = i >> 12, r = i & 4095;
  const float* W = (g == 0) ? Wq : (g == 1 ? Wk : Wv);
  outw[i] = f2bf(W[r]);
}

// ---------- prep: wcomb[e] = sum_eo Wo[eo][e]*Wfc[eo]; wcomb[64] = bo.Wfc + bfc ----------
__global__ void wcomb_kernel(const float* __restrict__ Wo, const float* __restrict__ Wfc,
                             const float* __restrict__ bo, const float* __restrict__ bfc,
                             float* __restrict__ wcomb){
  int e = threadIdx.x;
  float acc = 0.f;
  for (int eo = 0; eo < 64; ++eo) acc += Wo[eo * 64 + e] * Wfc[eo];
  wcomb[e] = acc;
  if (e == 0){
    float bc = bfc[0];
    for (int eo = 0; eo < 64; ++eo) bc += bo[eo] * Wfc[eo];
    wcomb[64] = bc;
  }
}

// ---------- main subnet kernel ----------
// 512 thr (8 waves), tile = 64 samples x one d. Wave tile in middle layers:
// 32 rows x 64 cols -> acc[2][4] = 32 accs/lane; combined regs ~90 so the
// (512,4) cap (=128) does NOT spill (R2 lesson: 64-acc set under a 128 cap
// spills to scratch). 4 waves/SIMD, 2 blocks/CU (64KB LDS).
// Grid is 1-D with an XCD-bijective d-clustering swizzle: each XCD sees a
// contiguous ~2-3 d slice so its per-d weights (~260KB each) stay L2-resident.
__global__ __launch_bounds__(512, 4) void subnet_kernel(
    const float* __restrict__ x, const float* __restrict__ W1, const float* __restrict__ b1,
    const float* __restrict__ bm, const float* __restrict__ bf_,
    const float* __restrict__ bq, const float* __restrict__ bk, const float* __restrict__ bv,
    const short* __restrict__ WmT, const short* __restrict__ WfT, const short* __restrict__ Wqkv,
    short* __restrict__ qkv)
{
  __shared__ short hbuf[64 * 256];   // 32 KB; tokens overlay first 8 KB at the end

  // XCD swizzle: 4352 = 8 * 544 (divides evenly -> simple form is bijective)
  int wg = blockIdx.x;
  int idx = (wg & 7) * 544 + (wg >> 3);
  const int d  = idx >> 8;          // 0..16  (d-major: same XCD -> few d's)
  const int m0 = (idx & 255) * 64;

  const int tid = threadIdx.x;
  const int lane = tid & 63, wave = tid >> 6;
  const int l15 = lane & 15, lhi = lane >> 4;

  // ---- phase 0: h0 = lrelu(x * W1 + b1) -> swizzled LDS [m][k], packed b32 writes
  {
    const int kp = tid & 127;            // k-pair index, k0 = 2*kp
    const int mg = tid >> 7;             // 0..3
    const float w1a = W1[d * H_N + 2 * kp],     w1b = W1[d * H_N + 2 * kp + 1];
    const float b1a = b1[d * H_N + 2 * kp],     b1b = b1[d * H_N + 2 * kp + 1];
    #pragma unroll
    for (int i = 0; i < 16; ++i){
      int m = mg * 16 + i;
      float xv = x[(size_t)(m0 + m) * D_N + d];
      unsigned lo = (unsigned short)f2bf(lrelu(xv * w1a + b1a));
      unsigned hi = (unsigned short)f2bf(lrelu(xv * w1b + b1b));
      int byte = m * 512 + ((((kp >> 2) ^ (m & 7))) << 4) + ((kp & 3) << 2);
      *(unsigned*)((char*)&hbuf[0] + byte) = lo | (hi << 16);
    }
  }
  __syncthreads();

  // ---- 2 middle layers: (64x256)@(256x256); wave tile 32r x 64c; in-place
  const int wr = wave >> 2, wc = wave & 3;
  for (int L = 0; L < 2; ++L){
    const short* Wt = WmT + (size_t)(L * D_N + d) * (H_N * H_N);   // [n][k] bf16
    const float* bias = bm + (size_t)(L * D_N + d) * H_N;
    f32x4 acc[2][4];
    #pragma unroll
    for (int a = 0; a < 2; ++a)
      #pragma unroll
      for (int c = 0; c < 4; ++c) acc[a][c] = (f32x4){0.f, 0.f, 0.f, 0.f};
    #pragma unroll
    for (int kk = 0; kk < 8; ++kk){
      bf16x8 af[2], bfr[4];
      #pragma unroll
      for (int fr = 0; fr < 2; ++fr){
        int row = wr * 32 + fr * 16 + l15;
        int cch = kk * 4 + lhi;
        af[fr] = *(const bf16x8*)((const char*)&hbuf[0] + row * 512 + ((cch ^ (row & 7)) << 4));
      }
      #pragma unroll
      for (int fc = 0; fc < 4; ++fc){
        int n = wc * 64 + fc * 16 + l15;
        bfr[fc] = *(const bf16x8*)(Wt + (size_t)n * H_N + kk * 32 + lhi * 8);
      }
      #pragma unroll
      for (int fr = 0; fr < 2; ++fr)
        #pragma unroll
        for (int fc = 0; fc < 4; ++fc)
          acc[fr][fc] = __builtin_amdgcn_mfma_f32_16x16x32_bf16(af[fr], bfr[fc], acc[fr][fc], 0, 0, 0);
    }
    __syncthreads();   // all waves done READING hbuf before in-place overwrite
    #pragma unroll
    for (int fr = 0; fr < 2; ++fr)
      #pragma unroll
      for (int fc = 0; fc < 4; ++fc)
        #pragma unroll
        for (int j = 0; j < 4; ++j){
          int row = wr * 32 + fr * 16 + lhi * 4 + j;
          int col = wc * 64 + fc * 16 + l15;
          float v = lrelu(acc[fr][fc][j] + bias[col]);
          int byte = row * 512 + ((((col >> 3) ^ (row & 7))) << 4) + ((col & 7) << 1);
          *(short*)((char*)&hbuf[0] + byte) = f2bf(v);
        }
    __syncthreads();
  }

  // ---- Wf layer: (64x256)@(256x64) + bf -> tokens overlay in hbuf [m][64]
  {
    const short* Wt = WfT + (size_t)d * (E_N * H_N);   // [e][k]
    const int r0 = (wave >> 1) * 16, c0 = (wave & 1) * 32;
    f32x4 acc[2];
    acc[0] = (f32x4){0.f, 0.f, 0.f, 0.f};
    acc[1] = (f32x4){0.f, 0.f, 0.f, 0.f};
    #pragma unroll
    for (int kk = 0; kk < 8; ++kk){
      int row = r0 + l15;
      int cch = kk * 4 + lhi;
      bf16x8 a = *(const bf16x8*)((const char*)&hbuf[0] + row * 512 + ((cch ^ (row & 7)) << 4));
      #pragma unroll
      for (int fc = 0; fc < 2; ++fc){
        int n = c0 + fc * 16 + l15;
        bf16x8 b = *(const bf16x8*)(Wt + (size_t)n * H_N + kk * 32 + lhi * 8);
        acc[fc] = __builtin_amdgcn_mfma_f32_16x16x32_bf16(a, b, acc[fc], 0, 0, 0);
      }
    }
    __syncthreads();   // all waves done reading hbuf before token overlay write
    #pragma unroll
    for (int fc = 0; fc < 2; ++fc)
      #pragma unroll
      for (int j = 0; j < 4; ++j){
        int row = r0 + lhi * 4 + j;
        int col = c0 + fc * 16 + l15;
        float v = acc[fc][j] + bf_[d * E_N + col];
        int byte = row * 128 + ((((col >> 3) ^ (row & 7))) << 4) + ((col & 7) << 1);
        *(short*)((char*)&hbuf[0] + byte) = f2bf(v);
      }
    __syncthreads();
  }

  // ---- fused QKV: tokens(64x64) @ [Wq|Wk|Wv]^T (64x192); wave tile 16r x 96c
  {
    const int r0 = (wave & 3) * 16, c0 = (wave >> 2) * 96;
    f32x4 acc[6];
    #pragma unroll
    for (int fc = 0; fc < 6; ++fc) acc[fc] = (f32x4){0.f, 0.f, 0.f, 0.f};
    #pragma unroll
    for (int kk = 0; kk < 2; ++kk){
      int row = r0 + l15;
      int cch = kk * 4 + lhi;
      bf16x8 a = *(const bf16x8*)((const char*)&hbuf[0] + row * 128 + ((cch ^ (row & 7)) << 4));
      #pragma unroll
      for (int fc = 0; fc < 6; ++fc){
        int n = c0 + fc * 16 + l15;
        bf16x8 b = *(const bf16x8*)(Wqkv + (size_t)n * E_N + kk * 32 + lhi * 8);
        acc[fc] = __builtin_amdgcn_mfma_f32_16x16x32_bf16(a, b, acc[fc], 0, 0, 0);
      }
    }
    #pragma unroll
    for (int fc = 0; fc < 6; ++fc)
      #pragma unroll
      for (int j = 0; j < 4; ++j){
        int n = c0 + fc * 16 + l15;
        int g = n >> 6, nl = n & 63;
        float bias = (g == 0) ? bq[nl] : (g == 1 ? bk[nl] : bv[nl]);
        int bg = m0 + r0 + lhi * 4 + j;
        float v = acc[fc][j] + bias;
        qkv[((size_t)bg * D_N + d) * 192 + n] = f2bf(v);
      }
  }
}

// ---------- attention + pool + folded head: one wave per sample ----------
__global__ __launch_bounds__(256, 4) void attn_kernel(
    const short* __restrict__ qkv, const float* __restrict__ wc, float* __restrict__ out)
{
  __shared__ short smem[4][17 * 192];     // per-wave sample tile, XOR-swizzled 16B chunks
  const int tid = threadIdx.x, lane = tid & 63, wave = tid >> 6;
  const int h = lane >> 4, iq = lane & 15;
  float wvec[16];
  #pragma unroll
  for (int u = 0; u < 16; ++u) wvec[u] = wc[h * 16 + u];
  const float bcomb = wc[64];

  for (int iter = 0; iter < 2; ++iter){
    int b = (blockIdx.x * 4 + wave) + iter * 8192;
    __syncthreads();
    const short* src = qkv + (size_t)b * (17 * 192);
    for (int g0 = lane; g0 < 408; g0 += 64){
      int i = g0 / 24, c = g0 % 24;
      bf16x8 v = *(const bf16x8*)(src + g0 * 8);
      *(bf16x8*)((char*)&smem[wave][0] + i * 384 + ((c ^ (i & 7)) << 4)) = v;
    }
    __syncthreads();

    float pool[16];
    #pragma unroll
    for (int u = 0; u < 16; ++u) pool[u] = 0.f;

    for (int t = 0; t < 2; ++t){
      int i = iq + 16 * t;
      if (i < 17){
        float q[16];
        #pragma unroll
        for (int u2 = 0; u2 < 2; ++u2){
          int cch = 2 * h + u2;
          bf16x8 v = *(const bf16x8*)((char*)&smem[wave][0] + i * 384 + ((cch ^ (i & 7)) << 4));
          #pragma unroll
          for (int z = 0; z < 8; ++z) q[u2 * 8 + z] = bf2f(v[z]);
        }
        float s[17];
        #pragma unroll
        for (int j = 0; j < 17; ++j){
          float a2 = 0.f;
          #pragma unroll
          for (int u2 = 0; u2 < 2; ++u2){
            int cch = 8 + 2 * h + u2;
            bf16x8 v = *(const bf16x8*)((char*)&smem[wave][0] + j * 384 + ((cch ^ (j & 7)) << 4));
            #pragma unroll
            for (int z = 0; z < 8; ++z) a2 += q[u2 * 8 + z] * bf2f(v[z]);
          }
          s[j] = a2 * 0.25f;                 // 1/sqrt(16)
        }
        float mx = s[0];
        #pragma unroll
        for (int j = 1; j < 17; ++j) mx = fmaxf(mx, s[j]);
        float sum = 0.f;
        #pragma unroll
        for (int j = 0; j < 17; ++j){ s[j] = __expf(s[j] - mx); sum += s[j]; }
        float inv = 1.f / sum;
        #pragma unroll
        for (int j = 0; j < 17; ++j){
          float w = s[j] * inv;
          #pragma unroll
          for (int u2 = 0; u2 < 2; ++u2){
            int cch = 16 + 2 * h + u2;
            bf16x8 v = *(const bf16x8*)((char*)&smem[wave][0] + j * 384 + ((cch ^ (j & 7)) << 4));
            #pragma unroll
            for (int z = 0; z < 8; ++z) pool[u2 * 8 + z] += w * bf2f(v[z]);
          }
        }
      }
    }
    // fold: out = lrelu( (1/17) * sum_{i,e} o_pre[i][e]*wcomb[e] + bcomb )
    float part = 0.f;
    #pragma unroll
    for (int u = 0; u < 16; ++u) part += pool[u] * wvec[u];
    #pragma unroll
    for (int off = 1; off < 64; off <<= 1) part += __shfl_xor(part, off);
    if (lane == 0) out[b] = lrelu(part * (1.f / 17.f) + bcomb);
  }
}

extern "C" void kernel_launch(void* const* d_in, const int* in_sizes, int n_in,
                              void* d_out, int out_size, void* d_ws, size_t ws_size,
                              hipStream_t stream)
{
  const float* x   = (const float*)d_in[0];
  const float* W1  = (const float*)d_in[1];
  const float* b1  = (const float*)d_in[2];
  const float* Wm  = (const float*)d_in[3];
  const float* bm  = (const float*)d_in[4];
  const float* Wf  = (const float*)d_in[5];
  const float* bf_ = (const float*)d_in[6];
  const float* Wq  = (const float*)d_in[7];
  const float* bq  = (const float*)d_in[8];
  const float* Wk  = (const float*)d_in[9];
  const float* bk  = (const float*)d_in[10];
  const float* Wv  = (const float*)d_in[11];
  const float* bv  = (const float*)d_in[12];
  const float* Wo  = (const float*)d_in[13];
  const float* bo  = (const float*)d_in[14];
  const float* Wfc = (const float*)d_in[15];
  const float* bfc = (const float*)d_in[16];
  float* out = (float*)d_out;
  (void)in_sizes; (void)n_in; (void)out_size; (void)ws_size;

  char* ws = (char*)d_ws;
  size_t off = 0;
  auto alloc = [&](size_t bytes) -> char* {
    char* p = ws + off;
    off = (off + bytes + 255) & ~(size_t)255;
    return p;
  };
  short* qkvb  = (short*)alloc((size_t)B_N * D_N * 192 * 2);      // ~102 MB
  short* WmT   = (short*)alloc((size_t)2 * D_N * H_N * H_N * 2);  // 4.5 MB
  short* WfT   = (short*)alloc((size_t)D_N * E_N * H_N * 2);      // 0.56 MB
  short* Wqkvb = (short*)alloc((size_t)192 * E_N * 2);
  float* wcomb = (float*)alloc(65 * sizeof(float));

  transpose_convert<<<dim3(8, 8, 2 * D_N), dim3(32, 8), 0, stream>>>(Wm, WmT, 256, 256);
  transpose_convert<<<dim3(2, 8, D_N),     dim3(32, 8), 0, stream>>>(Wf, WfT, 256, 64);
  convert_wqkv<<<dim3(48), dim3(256), 0, stream>>>(Wq, Wk, Wv, Wqkvb);
  wcomb_kernel<<<dim3(1), dim3(64), 0, stream>>>(Wo, Wfc, bo, bfc, wcomb);

  subnet_kernel<<<dim3(256 * D_N), dim3(512), 0, stream>>>(
      x, W1, b1, bm, bf_, bq, bk, bv, WmT, WfT, Wqkvb, qkvb);

  attn_kernel<<<dim3(2048), dim3(256), 0, stream>>>(qkvb, wcomb, out);
}

// Round 5
// 288.314 us; speedup vs baseline: 1.7255x; 1.7255x over previous
//
#include <hip/hip_runtime.h>
#include <hip/hip_bf16.h>

#define B_N   16384
#define D_N   17
#define H_N   256
#define E_N   64

typedef __attribute__((ext_vector_type(8))) short bf16x8;
typedef __attribute__((ext_vector_type(4))) float f32x4;

static __device__ __forceinline__ short f2bf(float f){
  unsigned u = __builtin_bit_cast(unsigned, f);
  unsigned r = (u + 0x7fffu + ((u >> 16) & 1u)) >> 16;   // RNE
  return (short)(unsigned short)r;
}
static __device__ __forceinline__ float bf2f(short s){
  unsigned u = ((unsigned)(unsigned short)s) << 16;
  return __builtin_bit_cast(float, u);
}
static __device__ __forceinline__ float lrelu(float v){ return v >= 0.f ? v : 0.01f * v; }

// async global->LDS, 16B per lane. LDS dest is wave-uniform base + lane*16.
static __device__ __forceinline__ void gload_lds16(const short* g, short* l){
  __builtin_amdgcn_global_load_lds(
      (const __attribute__((address_space(1))) unsigned int*)g,
      (__attribute__((address_space(3))) unsigned int*)l, 16, 0, 0);
}

// ---------- prep: fp32 (G,R,C) -> bf16 (G,C,R) ----------
__global__ void transpose_convert(const float* __restrict__ in, short* __restrict__ outp,
                                  int R, int C){
  __shared__ float tile[32][33];
  int g = blockIdx.z;
  const float* inp = in + (size_t)g * R * C;
  short* op = outp + (size_t)g * R * C;
  int c0 = blockIdx.x * 32, r0 = blockIdx.y * 32;
  for (int i = threadIdx.y; i < 32; i += 8)
    tile[i][threadIdx.x] = inp[(size_t)(r0 + i) * C + c0 + threadIdx.x];
  __syncthreads();
  for (int i = threadIdx.y; i < 32; i += 8)
    op[(size_t)(c0 + i) * R + r0 + threadIdx.x] = f2bf(tile[threadIdx.x][i]);
}

// ---------- prep: stack+convert Wq|Wk|Wv -> bf16 [192][64] ----------
__global__ void convert_wqkv(const float* __restrict__ Wq, const float* __restrict__ Wk,
                             const float* __restrict__ Wv, short* __restrict__ outw){
  int i = blockIdx.x * 256 + threadIdx.x;        // 0..12287
  int g = i >> 12, r = i & 4095;
  const float* W = (g == 0) ? Wq : (g == 1 ? Wk : Wv);
  outw[i] = f2bf(W[r]);
}

// ---------- prep: wcomb[e] = sum_eo Wo[eo][e]*Wfc[eo]; wcomb[64] = bo.Wfc + bfc ----------
__global__ void wcomb_kernel(const float* __restrict__ Wo, const float* __restrict__ Wfc,
                             const float* __restrict__ bo, const float* __restrict__ bfc,
                             float* __restrict__ wcomb){
  int e = threadIdx.x;
  float acc = 0.f;
  for (int eo = 0; eo < 64; ++eo) acc += Wo[eo * 64 + e] * Wfc[eo];
  wcomb[e] = acc;
  if (e == 0){
    float bc = bfc[0];
    for (int eo = 0; eo < 64; ++eo) bc += bo[eo] * Wfc[eo];
    wcomb[64] = bc;
  }
}

// Weight slice staging. Slice kk of a [rows][256] bf16 matrix = rows x 32 k.
// LDS layout: chunk index li = n*4 + c', where stored chunk c' = lhi ^ ((n>>1)&3)
// (swizzle applied on the GLOBAL source address; gload_lds writes linearly).
// Read side: b128 at byte n*64 + ((lhi ^ ((n>>1)&3))<<4) -> 2-way banks (free).
static __device__ __forceinline__ void stage_w256(const short* Wt, int kk, short* wb,
                                                  int wave, int lane){
  #pragma unroll
  for (int r = 0; r < 4; ++r){
    int li = r * 256 + wave * 64 + lane;            // 16B-chunk index, 0..1023
    int n  = li >> 2;
    int cc = (li & 3) ^ ((n >> 1) & 3);
    const short* src = Wt + n * 256 + kk * 32 + cc * 8;
    short* dst = wb + (size_t)(r * 256 + wave * 64) * 8;   // wave-uniform base
    gload_lds16(src, dst);
  }
}
static __device__ __forceinline__ void stage_w64(const short* Wt, int kk, short* wb,
                                                 int wave, int lane){
  int li = wave * 64 + lane;                        // 0..255 chunks (4KB)
  int n  = li >> 2;
  int cc = (li & 3) ^ ((n >> 1) & 3);
  const short* src = Wt + n * 256 + kk * 32 + cc * 8;
  short* dst = wb + (size_t)(wave * 64) * 8;
  gload_lds16(src, dst);
}

// ---------- main subnet kernel ----------
// 256 thr (4 waves), tile = 64 samples x one d. R3 shape: wave = 64-col slice,
// acc[4][4] (64 accs). Weights double-buffered in LDS via global_load_lds:
// per kk-step {stage kk+1 -> read frags kk -> 16 MFMA -> barrier}; the barrier's
// vmcnt drain lands after ~300cyc of compute cover (2-phase pattern) instead of
// naked L2 latency in front of the MFMAs (R3: MfmaUtil 12.5%).
// LDS 64KB -> 2 blocks/CU; (256,2) NOT tighter (R2: harder cap spills accs).
__global__ __launch_bounds__(256, 2) void subnet_kernel(
    const float* __restrict__ x, const float* __restrict__ W1, const float* __restrict__ b1,
    const float* __restrict__ bm, const float* __restrict__ bf_,
    const float* __restrict__ bq, const float* __restrict__ bk, const float* __restrict__ bv,
    const short* __restrict__ WmT, const short* __restrict__ WfT, const short* __restrict__ Wqkv,
    short* __restrict__ qkv)
{
  __shared__ short hbuf[64 * 256];       // 32 KB activations (tokens overlay head)
  __shared__ short wbuf[2][256 * 32];    // 2 x 16 KB weight k-slices

  // XCD swizzle: 4352 = 8*544, d-major so each XCD sees ~2 d's (weights L2-resident)
  int wg = blockIdx.x;
  int idx = (wg & 7) * 544 + (wg >> 3);
  const int d  = idx >> 8;
  const int m0 = (idx & 255) * 64;

  const int tid = threadIdx.x;
  const int lane = tid & 63, wave = tid >> 6;
  const int l15 = lane & 15, lhi = lane >> 4;

  const short* WtL0 = WmT + (size_t)(0 * D_N + d) * (H_N * H_N);
  const short* WtL1 = WmT + (size_t)(1 * D_N + d) * (H_N * H_N);
  const short* Wfd  = WfT + (size_t)d * (E_N * H_N);

  // prologue prefetch: L0 slice 0 flies during phase 0
  stage_w256(WtL0, 0, &wbuf[0][0], wave, lane);

  // ---- phase 0: h0 = lrelu(x*W1+b1) -> swizzled LDS [m][k], packed b32 writes
  {
    const int kp = tid & 127;            // k-pair, k0 = 2*kp
    const int mh = tid >> 7;             // 0/1 -> m half
    const float w1a = W1[d * H_N + 2 * kp], w1b = W1[d * H_N + 2 * kp + 1];
    const float b1a = b1[d * H_N + 2 * kp], b1b = b1[d * H_N + 2 * kp + 1];
    #pragma unroll
    for (int i = 0; i < 32; ++i){
      int m = mh * 32 + i;
      float xv = x[(size_t)(m0 + m) * D_N + d];
      unsigned lo = (unsigned short)f2bf(lrelu(xv * w1a + b1a));
      unsigned hi = (unsigned short)f2bf(lrelu(xv * w1b + b1b));
      int byte = m * 512 + ((((kp >> 2) ^ (m & 7))) << 4) + ((kp & 3) << 2);
      *(unsigned*)((char*)&hbuf[0] + byte) = lo | (hi << 16);
    }
  }
  __syncthreads();   // drains phase-0 LDS writes AND the staged slice 0

  // ---- 2 middle layers: (64x256)@(256x256); wave = 64-col slice; in-place
  for (int L = 0; L < 2; ++L){
    const short* Wt = L ? WtL1 : WtL0;
    const float* bias = bm + (size_t)(L * D_N + d) * H_N;
    f32x4 acc[4][4];
    #pragma unroll
    for (int a = 0; a < 4; ++a)
      #pragma unroll
      for (int c = 0; c < 4; ++c) acc[a][c] = (f32x4){0.f, 0.f, 0.f, 0.f};

    for (int kk = 0; kk < 8; ++kk){
      // stage next slice (or next phase's slice 0) into the other buffer
      if (kk < 7)      stage_w256(Wt,   kk + 1, &wbuf[(kk + 1) & 1][0], wave, lane);
      else if (L == 0) stage_w256(WtL1, 0,      &wbuf[0][0],            wave, lane);
      else             stage_w64 (Wfd,  0,      &wbuf[0][0],            wave, lane);

      const short* wb = &wbuf[kk & 1][0];
      bf16x8 af[4], bfr[4];
      #pragma unroll
      for (int fr = 0; fr < 4; ++fr){
        int row = fr * 16 + l15;
        int cch = kk * 4 + lhi;
        af[fr] = *(const bf16x8*)((const char*)&hbuf[0] + row * 512 + ((cch ^ (row & 7)) << 4));
      }
      #pragma unroll
      for (int fc = 0; fc < 4; ++fc){
        int n = wave * 64 + fc * 16 + l15;
        bfr[fc] = *(const bf16x8*)((const char*)wb + n * 64 + ((lhi ^ ((n >> 1) & 3)) << 4));
      }
      #pragma unroll
      for (int fr = 0; fr < 4; ++fr)
        #pragma unroll
        for (int fc = 0; fc < 4; ++fc)
          acc[fr][fc] = __builtin_amdgcn_mfma_f32_16x16x32_bf16(af[fr], bfr[fc], acc[fr][fc], 0, 0, 0);
      __syncthreads();   // separates reads from next staging/overwrite; drains vmcnt
    }
    // bias + lrelu, bf16 back in place (all reads done at last barrier)
    #pragma unroll
    for (int fr = 0; fr < 4; ++fr)
      #pragma unroll
      for (int fc = 0; fc < 4; ++fc)
        #pragma unroll
        for (int j = 0; j < 4; ++j){
          int row = fr * 16 + lhi * 4 + j;
          int col = wave * 64 + fc * 16 + l15;
          float v = lrelu(acc[fr][fc][j] + bias[col]);
          int byte = row * 512 + ((((col >> 3) ^ (row & 7))) << 4) + ((col & 7) << 1);
          *(short*)((char*)&hbuf[0] + byte) = f2bf(v);
        }
    __syncthreads();
  }

  // ---- Wf layer: (64x256)@(256x64) + bf -> tokens overlay in hbuf [m][64]
  {
    const int r0 = wave * 16;
    f32x4 acc[4];
    #pragma unroll
    for (int fc = 0; fc < 4; ++fc) acc[fc] = (f32x4){0.f, 0.f, 0.f, 0.f};
    for (int kk = 0; kk < 8; ++kk){
      if (kk < 7) stage_w64(Wfd, kk + 1, &wbuf[(kk + 1) & 1][0], wave, lane);
      const short* wb = &wbuf[kk & 1][0];
      int row = r0 + l15;
      int cch = kk * 4 + lhi;
      bf16x8 a = *(const bf16x8*)((const char*)&hbuf[0] + row * 512 + ((cch ^ (row & 7)) << 4));
      #pragma unroll
      for (int fc = 0; fc < 4; ++fc){
        int n = fc * 16 + l15;
        bf16x8 b = *(const bf16x8*)((const char*)wb + n * 64 + ((lhi ^ ((n >> 1) & 3)) << 4));
        acc[fc] = __builtin_amdgcn_mfma_f32_16x16x32_bf16(a, b, acc[fc], 0, 0, 0);
      }
      __syncthreads();
    }
    #pragma unroll
    for (int fc = 0; fc < 4; ++fc)
      #pragma unroll
      for (int j = 0; j < 4; ++j){
        int row = r0 + lhi * 4 + j;
        int col = fc * 16 + l15;
        float v = acc[fc][j] + bf_[d * E_N + col];
        int byte = row * 128 + ((((col >> 3) ^ (row & 7))) << 4) + ((col & 7) << 1);
        *(short*)((char*)&hbuf[0] + byte) = f2bf(v);
      }
    __syncthreads();
  }

  // ---- fused QKV: tokens(64x64) @ [Wq|Wk|Wv]^T (64x192); wave = 48-col slice
  // Wqkv is 24KB shared by ALL blocks -> L1/L2-hot; direct global loads fine.
  {
    f32x4 acc[4][3];
    #pragma unroll
    for (int fr = 0; fr < 4; ++fr)
      #pragma unroll
      for (int fc = 0; fc < 3; ++fc) acc[fr][fc] = (f32x4){0.f, 0.f, 0.f, 0.f};
    #pragma unroll
    for (int kk = 0; kk < 2; ++kk){
      bf16x8 af[4];
      #pragma unroll
      for (int fr = 0; fr < 4; ++fr){
        int row = fr * 16 + l15;
        int cch = kk * 4 + lhi;
        af[fr] = *(const bf16x8*)((const char*)&hbuf[0] + row * 128 + ((cch ^ (row & 7)) << 4));
      }
      bf16x8 bb[3];
      #pragma unroll
      for (int fc = 0; fc < 3; ++fc){
        int n = wave * 48 + fc * 16 + l15;
        bb[fc] = *(const bf16x8*)(Wqkv + (size_t)n * E_N + kk * 32 + lhi * 8);
      }
      #pragma unroll
      for (int fr = 0; fr < 4; ++fr)
        #pragma unroll
        for (int fc = 0; fc < 3; ++fc)
          acc[fr][fc] = __builtin_amdgcn_mfma_f32_16x16x32_bf16(af[fr], bb[fc], acc[fr][fc], 0, 0, 0);
    }
    #pragma unroll
    for (int fr = 0; fr < 4; ++fr)
      #pragma unroll
      for (int fc = 0; fc < 3; ++fc)
        #pragma unroll
        for (int j = 0; j < 4; ++j){
          int n = wave * 48 + fc * 16 + l15;
          int g = n >> 6, nl = n & 63;
          float bias = (g == 0) ? bq[nl] : (g == 1 ? bk[nl] : bv[nl]);
          int bg = m0 + fr * 16 + lhi * 4 + j;
          float v = acc[fr][fc][j] + bias;
          qkv[((size_t)bg * D_N + d) * 192 + n] = f2bf(v);
        }
  }
}

// ---------- attention + pool + folded head: one wave per sample ----------
__global__ __launch_bounds__(256, 4) void attn_kernel(
    const short* __restrict__ qkv, const float* __restrict__ wc, float* __restrict__ out)
{
  __shared__ short smem[4][17 * 192];     // per-wave sample tile, XOR-swizzled 16B chunks
  const int tid = threadIdx.x, lane = tid & 63, wave = tid >> 6;
  const int h = lane >> 4, iq = lane & 15;
  float wvec[16];
  #pragma unroll
  for (int u = 0; u < 16; ++u) wvec[u] = wc[h * 16 + u];
  const float bcomb = wc[64];

  for (int iter = 0; iter < 2; ++iter){
    int b = (blockIdx.x * 4 + wave) + iter * 8192;
    __syncthreads();
    const short* src = qkv + (size_t)b * (17 * 192);
    for (int g0 = lane; g0 < 408; g0 += 64){
      int i = g0 / 24, c = g0 % 24;
      bf16x8 v = *(const bf16x8*)(src + g0 * 8);
      *(bf16x8*)((char*)&smem[wave][0] + i * 384 + ((c ^ (i & 7)) << 4)) = v;
    }
    __syncthreads();

    float pool[16];
    #pragma unroll
    for (int u = 0; u < 16; ++u) pool[u] = 0.f;

    for (int t = 0; t < 2; ++t){
      int i = iq + 16 * t;
      if (i < 17){
        float q[16];
        #pragma unroll
        for (int u2 = 0; u2 < 2; ++u2){
          int cch = 2 * h + u2;
          bf16x8 v = *(const bf16x8*)((char*)&smem[wave][0] + i * 384 + ((cch ^ (i & 7)) << 4));
          #pragma unroll
          for (int z = 0; z < 8; ++z) q[u2 * 8 + z] = bf2f(v[z]);
        }
        float s[17];
        #pragma unroll
        for (int j = 0; j < 17; ++j){
          float a2 = 0.f;
          #pragma unroll
          for (int u2 = 0; u2 < 2; ++u2){
            int cch = 8 + 2 * h + u2;
            bf16x8 v = *(const bf16x8*)((char*)&smem[wave][0] + j * 384 + ((cch ^ (j & 7)) << 4));
            #pragma unroll
            for (int z = 0; z < 8; ++z) a2 += q[u2 * 8 + z] * bf2f(v[z]);
          }
          s[j] = a2 * 0.25f;                 // 1/sqrt(16)
        }
        float mx = s[0];
        #pragma unroll
        for (int j = 1; j < 17; ++j) mx = fmaxf(mx, s[j]);
        float sum = 0.f;
        #pragma unroll
        for (int j = 0; j < 17; ++j){ s[j] = __expf(s[j] - mx); sum += s[j]; }
        float inv = 1.f / sum;
        #pragma unroll
        for (int j = 0; j < 17; ++j){
          float w = s[j] * inv;
          #pragma unroll
          for (int u2 = 0; u2 < 2; ++u2){
            int cch = 16 + 2 * h + u2;
            bf16x8 v = *(const bf16x8*)((char*)&smem[wave][0] + j * 384 + ((cch ^ (j & 7)) << 4));
            #pragma unroll
            for (int z = 0; z < 8; ++z) pool[u2 * 8 + z] += w * bf2f(v[z]);
          }
        }
      }
    }
    // fold: out = lrelu( (1/17) * sum_{i,e} o_pre[i][e]*wcomb[e] + bcomb )
    float part = 0.f;
    #pragma unroll
    for (int u = 0; u < 16; ++u) part += pool[u] * wvec[u];
    #pragma unroll
    for (int off = 1; off < 64; off <<= 1) part += __shfl_xor(part, off);
    if (lane == 0) out[b] = lrelu(part * (1.f / 17.f) + bcomb);
  }
}

extern "C" void kernel_launch(void* const* d_in, const int* in_sizes, int n_in,
                              void* d_out, int out_size, void* d_ws, size_t ws_size,
                              hipStream_t stream)
{
  const float* x   = (const float*)d_in[0];
  const float* W1  = (const float*)d_in[1];
  const float* b1  = (const float*)d_in[2];
  const float* Wm  = (const float*)d_in[3];
  const float* bm  = (const float*)d_in[4];
  const float* Wf  = (const float*)d_in[5];
  const float* bf_ = (const float*)d_in[6];
  const float* Wq  = (const float*)d_in[7];
  const float* bq  = (const float*)d_in[8];
  const float* Wk  = (const float*)d_in[9];
  const float* bk  = (const float*)d_in[10];
  const float* Wv  = (const float*)d_in[11];
  const float* bv  = (const float*)d_in[12];
  const float* Wo  = (const float*)d_in[13];
  const float* bo  = (const float*)d_in[14];
  const float* Wfc = (const float*)d_in[15];
  const float* bfc = (const float*)d_in[16];
  float* out = (float*)d_out;
  (void)in_sizes; (void)n_in; (void)out_size; (void)ws_size;

  char* ws = (char*)d_ws;
  size_t off = 0;
  auto alloc = [&](size_t bytes) -> char* {
    char* p = ws + off;
    off = (off + bytes + 255) & ~(size_t)255;
    return p;
  };
  short* qkvb  = (short*)alloc((size_t)B_N * D_N * 192 * 2);      // ~102 MB
  short* WmT   = (short*)alloc((size_t)2 * D_N * H_N * H_N * 2);  // 4.5 MB
  short* WfT   = (short*)alloc((size_t)D_N * E_N * H_N * 2);      // 0.56 MB
  short* Wqkvb = (short*)alloc((size_t)192 * E_N * 2);
  float* wcomb = (float*)alloc(65 * sizeof(float));

  transpose_convert<<<dim3(8, 8, 2 * D_N), dim3(32, 8), 0, stream>>>(Wm, WmT, 256, 256);
  transpose_convert<<<dim3(2, 8, D_N),     dim3(32, 8), 0, stream>>>(Wf, WfT, 256, 64);
  convert_wqkv<<<dim3(48), dim3(256), 0, stream>>>(Wq, Wk, Wv, Wqkvb);
  wcomb_kernel<<<dim3(1), dim3(64), 0, stream>>>(Wo, Wfc, bo, bfc, wcomb);

  subnet_kernel<<<dim3(256 * D_N), dim3(256), 0, stream>>>(
      x, W1, b1, bm, bf_, bq, bk, bv, WmT, WfT, Wqkvb, qkvb);

  attn_kernel<<<dim3(2048), dim3(256), 0, stream>>>(qkvb, wcomb, out);
}